// Round 5
// baseline (567.265 us; speedup 1.0000x reference)
//
#include <hip/hip_runtime.h>

typedef __bf16 bf16;
typedef __bf16 bf16x8 __attribute__((ext_vector_type(8)));
typedef float  f32x4  __attribute__((ext_vector_type(4)));

#define MFMA16(a, b, c) __builtin_amdgcn_mfma_f32_16x16x32_bf16((a), (b), (c), 0, 0, 0)

// async global->LDS, 16 B per lane. LDS dest = wave-uniform base + lane*16.
__device__ inline void gl_lds16(const bf16* g, bf16* l) {
  __builtin_amdgcn_global_load_lds(
      (const __attribute__((address_space(1))) void*)g,
      (__attribute__((address_space(3))) void*)l, 16, 0, 0);
}

__device__ inline bf16x8 cvt8(const float* __restrict__ f) {
  float4 a = *(const float4*)f;
  float4 b = *(const float4*)(f + 4);
  bf16x8 r;
  r[0] = (bf16)a.x; r[1] = (bf16)a.y; r[2] = (bf16)a.z; r[3] = (bf16)a.w;
  r[4] = (bf16)b.x; r[5] = (bf16)b.y; r[6] = (bf16)b.z; r[7] = (bf16)b.w;
  return r;
}

// ---------------------------------------------------------------------------
// fp32 -> bf16 bulk convert (8 elems/thread)
// ---------------------------------------------------------------------------
__global__ void cvt_f32_bf16(const float* __restrict__ src, bf16* __restrict__ dst,
                             int n8) {
  int i = blockIdx.x * 256 + threadIdx.x;
  if (i >= n8) return;
  *(bf16x8*)(dst + (size_t)i * 8) = cvt8(src + (size_t)i * 8);
}

// ---------------------------------------------------------------------------
// GEMM (m97 structure): C[M,N] = A[M,K] @ W[N,K]^T, bf16 MFMA, fp32 accum.
// 128x128 tile, BK=64, 4 waves (2x2), 4x4 16x16x32 MFMA per wave.
// LDS: UNPADDED row-major As/Bs[128][64] staged via global_load_lds width=16
// (wave-uniform dst + lane*16 — layout is exactly lane-order contiguous).
// AF32: A staged via VGPR cvt8 instead (fp32 source, e.g. key_t/value).
// Split output: blocks with n0 >= Nsplit write C1 (and read A1) — lets
// K-proj and V-proj run as ONE N=1024 dispatch (Wk||Wv contiguous).
// ---------------------------------------------------------------------------
template <bool AF32, bool OUTF32>
__global__ __launch_bounds__(256) void gemm_bt(const void* __restrict__ Ap0,
                                               const void* __restrict__ Ap1,
                                               const bf16* __restrict__ W,
                                               void* __restrict__ C0,
                                               void* __restrict__ C1,
                                               int Nsplit, int ld0, int ld1,
                                               int M, int N, int K) {
  __shared__ alignas(16) bf16 As[128 * 64];
  __shared__ alignas(16) bf16 Bs[128 * 64];

  const int tid  = threadIdx.x;
  const int wave = tid >> 6, lane = tid & 63;
  const int wm = wave >> 1, wn = wave & 1;
  const int lr = lane & 15, quad = lane >> 4;
  const int m0 = blockIdx.y * 128, n0 = blockIdx.x * 128;

  const bool second = (n0 >= Nsplit);
  const void* Ap = second ? Ap1 : Ap0;

  f32x4 vzero = {0.f, 0.f, 0.f, 0.f};
  f32x4 acc[4][4];
#pragma unroll
  for (int mt = 0; mt < 4; ++mt)
#pragma unroll
    for (int nt = 0; nt < 4; ++nt) acc[mt][nt] = vzero;

  for (int k0 = 0; k0 < K; k0 += 64) {
    // ---- stage B tile (128x64) via async global->LDS: 16 instrs, 4/wave ----
#pragma unroll
    for (int j = 0; j < 4; ++j) {
      int c   = wave * 4 + j;              // chunk 0..15 = rows 8c..8c+7
      int row = c * 8 + (lane >> 3);
      int col = (lane & 7) * 8;
      gl_lds16(W + (size_t)(n0 + row) * K + k0 + col, Bs + c * 512);
    }
    // ---- stage A tile ----
    if (AF32) {
#pragma unroll
      for (int i = 0; i < 4; ++i) {
        int q   = i * 256 + tid;           // 0..1023
        int row = q >> 3;
        int c8  = q & 7;
        *(bf16x8*)(As + row * 64 + c8 * 8) =
            cvt8((const float*)Ap + (size_t)(m0 + row) * K + k0 + c8 * 8);
      }
    } else {
#pragma unroll
      for (int j = 0; j < 4; ++j) {
        int c   = wave * 4 + j;
        int row = c * 8 + (lane >> 3);
        int col = (lane & 7) * 8;
        gl_lds16((const bf16*)Ap + (size_t)(m0 + row) * K + k0 + col, As + c * 512);
      }
    }
    __syncthreads();

#pragma unroll
    for (int s = 0; s < 2; ++s) {
      bf16x8 af[4], bfg[4];
#pragma unroll
      for (int mt = 0; mt < 4; ++mt) {
        int m = wm * 64 + mt * 16 + lr;
        af[mt] = *(const bf16x8*)(As + m * 64 + s * 32 + quad * 8);
      }
#pragma unroll
      for (int nt = 0; nt < 4; ++nt) {
        int n = wn * 64 + nt * 16 + lr;
        bfg[nt] = *(const bf16x8*)(Bs + n * 64 + s * 32 + quad * 8);
      }
#pragma unroll
      for (int mt = 0; mt < 4; ++mt)
#pragma unroll
        for (int nt = 0; nt < 4; ++nt)
          acc[mt][nt] = MFMA16(af[mt], bfg[nt], acc[mt][nt]);
    }
    __syncthreads();
  }

  // epilogue: C/D layout col = lane&15, row = quad*4 + e   [HW-verified m89]
  void* Cb = second ? C1 : C0;
  const int ld = second ? ld1 : ld0;
  const int nb = second ? n0 - Nsplit : n0;
#pragma unroll
  for (int mt = 0; mt < 4; ++mt) {
    int row = m0 + wm * 64 + mt * 16 + quad * 4;
#pragma unroll
    for (int nt = 0; nt < 4; ++nt) {
      int col = nb + wn * 64 + nt * 16 + lr;
#pragma unroll
      for (int e = 0; e < 4; ++e) {
        if (OUTF32)
          ((float*)Cb)[(size_t)(row + e) * ld + col] = acc[mt][nt][e];
        else
          ((bf16*)Cb)[(size_t)(row + e) * ld + col] = (bf16)acc[mt][nt][e];
      }
    }
  }
}

// ---------------------------------------------------------------------------
// RoPE + clip (+scale fold), in place, vectorized: 8 (j,j+64) pairs/thread.
// X is (4096 rows) x (heads*128); angle = pos * 10000^(-j/64); clip +-50.
// ---------------------------------------------------------------------------
__global__ void rope_clip(bf16* __restrict__ X, int heads, float scl) {
  int tpr = heads * 8;  // 8-wide groups per row
  int idx = blockIdx.x * 256 + threadIdx.x;
  if (idx >= 4096 * tpr) return;
  int r = idx / tpr;
  int rem = idx - r * tpr;
  int h = rem >> 3, j0 = (rem & 7) * 8;
  int l = r & 2047;
  size_t base = (size_t)r * (heads * 128) + h * 128 + j0;
  bf16x8 x1 = *(const bf16x8*)(X + base);
  bf16x8 x2 = *(const bf16x8*)(X + base + 64);
  bf16x8 y1, y2;
#pragma unroll
  for (int t = 0; t < 8; ++t) {
    int j = j0 + t;
    float inv = expf(-(float)j * (9.210340371976184f / 64.0f));
    float s, c;
    sincosf((float)l * inv, &s, &c);
    float a = (float)x1[t], b = (float)x2[t];
    float u = a * c - b * s;
    float v = a * s + b * c;
    y1[t] = (bf16)(fminf(fmaxf(u, -50.f), 50.f) * scl);
    y2[t] = (bf16)(fminf(fmaxf(v, -50.f), 50.f) * scl);
  }
  *(bf16x8*)(X + base)      = y1;
  *(bf16x8*)(X + base + 64) = y2;
}

// ---------------------------------------------------------------------------
// Transpose per batch: in (R x Cc) -> out (Cc x R).  R=2048, Cc=512.
// ---------------------------------------------------------------------------
__global__ void transpose_bf16(const bf16* __restrict__ in, bf16* __restrict__ out,
                               int R, int Cc) {
  __shared__ bf16 t[32][33];
  int b = blockIdx.z;
  const bf16* ip = in + (size_t)b * R * Cc;
  bf16* op = out + (size_t)b * R * Cc;
  int c0 = blockIdx.x * 32, r0 = blockIdx.y * 32;
  int lx = threadIdx.x, ly = threadIdx.y;  // 32 x 8
#pragma unroll
  for (int i = 0; i < 32; i += 8)
    t[ly + i][lx] = ip[(size_t)(r0 + ly + i) * Cc + c0 + lx];
  __syncthreads();
#pragma unroll
  for (int i = 0; i < 32; i += 8)
    op[(size_t)(c0 + ly + i) * R + r0 + lx] = t[lx][ly + i];
}

// ---------------------------------------------------------------------------
// Flash attention v3, causal, GQA (16 qh -> 4 kvh), DK=128, L=2048.
// 4 waves/block, 64 q-rows/block, 64-key chunks; fixed-max softmax;
// K/V staged via global_load_lds into UNPADDED Ks[64][128] / Vs[128][64];
// balanced causal swizzle of q-tiles (pair light i with heavy 31-i).
// Q pre-scaled by 1/sqrt(128) in rope_clip.
// ---------------------------------------------------------------------------
__global__ __launch_bounds__(256) void flash(const bf16* __restrict__ Q,
                                             const bf16* __restrict__ Kp,
                                             const bf16* __restrict__ Vt,
                                             bf16* __restrict__ Ctx) {
  __shared__ alignas(16) bf16 Ks[64 * 128];   // 16 KB
  __shared__ alignas(16) bf16 Vs[128 * 64];   // 16 KB
  __shared__ alignas(16) bf16 Ps[4 * 16 * 72];

  const int tid  = threadIdx.x;
  const int wave = tid >> 6, lane = tid & 63;
  const int lr = lane & 15, quad = lane >> 4;
  const int bh = blockIdx.y;
  const int b = bh >> 4, h = bh & 15, hk = h >> 2;
  const int ix = blockIdx.x;
  const int qt = (ix & 1) ? (31 - (ix >> 1)) : (ix >> 1);  // balance causal work
  const int q0 = qt * 64;
  const int qb = q0 + wave * 16;

  const bf16* qptr = Q + ((size_t)(b * 2048 + qb + lr)) * 2048 + h * 128 + quad * 8;
  bf16x8 qf[4];
#pragma unroll
  for (int ks = 0; ks < 4; ++ks) qf[ks] = *(const bf16x8*)(qptr + ks * 32);

  f32x4 vzero = {0.f, 0.f, 0.f, 0.f};
  f32x4 o[8];
#pragma unroll
  for (int dt = 0; dt < 8; ++dt) o[dt] = vzero;
  float fls[4] = {0.f, 0.f, 0.f, 0.f};

  const bf16* kbase = Kp + (size_t)(b * 2048) * 512 + hk * 128;
  const bf16* vbase = Vt + ((size_t)(b * 512 + hk * 128)) * 2048;

  const int kmax = q0 + 64;
  for (int k0 = 0; k0 < kmax; k0 += 64) {
    // stage K (64x128): chunk c = 4 rows; V^T (128x64): chunk c = 8 rows
#pragma unroll
    for (int j = 0; j < 4; ++j) {
      int c = wave * 4 + j;
      int krow = c * 4 + (lane >> 4), kcol = (lane & 15) * 8;
      gl_lds16(kbase + (size_t)(k0 + krow) * 512 + kcol, Ks + c * 512);
      int vrow = c * 8 + (lane >> 3), vcol = (lane & 7) * 8;
      gl_lds16(vbase + (size_t)vrow * 2048 + k0 + vcol, Vs + c * 512);
    }
    __syncthreads();

    if (k0 <= qb + 15) {  // wave-uniform causal skip
      f32x4 s[4] = {vzero, vzero, vzero, vzero};
#pragma unroll
      for (int ks = 0; ks < 4; ++ks) {
#pragma unroll
        for (int kt = 0; kt < 4; ++kt) {
          bf16x8 kf = *(const bf16x8*)(Ks + (kt * 16 + lr) * 128 + ks * 32 + quad * 8);
          s[kt] = MFMA16(qf[ks], kf, s[kt]);
        }
      }
      bf16* pw = Ps + wave * (16 * 72);
#pragma unroll
      for (int kt = 0; kt < 4; ++kt) {
        int kid = k0 + kt * 16 + lr;
#pragma unroll
        for (int e = 0; e < 4; ++e) {
          int qi = qb + quad * 4 + e;
          float p = (kid <= qi) ? __expf(s[kt][e]) : 0.f;
          fls[e] += p;
          pw[(quad * 4 + e) * 72 + kt * 16 + lr] = (bf16)p;
        }
      }
#pragma unroll
      for (int ks2 = 0; ks2 < 2; ++ks2) {
        bf16x8 pf = *(const bf16x8*)(pw + lr * 72 + ks2 * 32 + quad * 8);
#pragma unroll
        for (int dt = 0; dt < 8; ++dt) {
          bf16x8 vf = *(const bf16x8*)(Vs + (dt * 16 + lr) * 64 + ks2 * 32 + quad * 8);
          o[dt] = MFMA16(pf, vf, o[dt]);
        }
      }
    }
    __syncthreads();
  }

  // one-time denominator reduce across the 16 key-lanes
#pragma unroll
  for (int e = 0; e < 4; ++e) {
    float s = fls[e];
    s += __shfl_xor(s, 1);
    s += __shfl_xor(s, 2);
    s += __shfl_xor(s, 4);
    s += __shfl_xor(s, 8);
    fls[e] = 1.0f / s;
  }

  bf16* cptr = Ctx + ((size_t)(b * 2048 + qb + quad * 4)) * 2048 + h * 128 + lr;
#pragma unroll
  for (int dt = 0; dt < 8; ++dt)
#pragma unroll
    for (int e = 0; e < 4; ++e)
      cptr[(size_t)e * 2048 + dt * 16] = (bf16)(o[dt][e] * fls[e]);
}

// ---------------------------------------------------------------------------
extern "C" void kernel_launch(void* const* d_in, const int* in_sizes, int n_in,
                              void* d_out, int out_size, void* d_ws, size_t ws_size,
                              hipStream_t stream) {
  (void)in_sizes; (void)n_in; (void)out_size; (void)ws_size;
  const float* query = (const float*)d_in[0];
  const float* key_t = (const float*)d_in[1];
  const float* value = (const float*)d_in[2];
  // d_in[3] = mask (causal tril) — applied analytically
  const float* Wq = (const float*)d_in[4];
  const float* Wk = (const float*)d_in[5];
  const float* Wv = (const float*)d_in[6];
  const float* Wo = (const float*)d_in[7];

  const size_t MB = 1024ull * 1024ull;
  char* ws  = (char*)d_ws;
  bf16* qbf = (bf16*)(ws);                  // [0,16)  query bf16
  bf16* wqb = (bf16*)(ws + 16 * MB);        // [16,24)
  bf16* wkb = (bf16*)(ws + 24 * MB);        // [24,26)  Wk bf16
  bf16* wvb = (bf16*)(ws + 26 * MB);        // [26,28)  Wv bf16 (contiguous with Wk!)
  bf16* wob = (bf16*)(ws + 28 * MB);        // [28,36)
  bf16* Qb  = (bf16*)(ws + 36 * MB);        // [36,52)
  bf16* Kb  = (bf16*)(ws + 52 * MB);        // [52,56)
  bf16* Vb  = (bf16*)(ws + 56 * MB);        // [56,60)
  bf16* Vtb = (bf16*)(ws + 60 * MB);        // [60,64)
  bf16* Ctx = qbf;                          // alias: qbf dead after Q-proj

  cvt_f32_bf16<<<4096, 256, 0, stream>>>(query, qbf, 1048576);
  cvt_f32_bf16<<<2048, 256, 0, stream>>>(Wq, wqb, 524288);
  cvt_f32_bf16<<<512, 256, 0, stream>>>(Wk, wkb, 131072);
  cvt_f32_bf16<<<512, 256, 0, stream>>>(Wv, wvb, 131072);
  cvt_f32_bf16<<<2048, 256, 0, stream>>>(Wo, wob, 524288);

  // Q-projection: pure-bf16, global_load_lds both operands
  gemm_bt<false, false><<<dim3(16, 32), 256, 0, stream>>>(
      qbf, qbf, wqb, Qb, Qb, 2048, 2048, 2048, 4096, 2048, 2048);

  // fused K+V projection: N=1024 (Wk||Wv), A = key_t / value per half, fp32 A
  gemm_bt<true, false><<<dim3(8, 32), 256, 0, stream>>>(
      key_t, value, wkb, Kb, Vb, 512, 512, 512, 4096, 1024, 2048);

  rope_clip<<<2048, 256, 0, stream>>>(Qb, 16, 0.08838834764831845f);
  rope_clip<<<512, 256, 0, stream>>>(Kb, 4, 1.0f);

  transpose_bf16<<<dim3(16, 64, 2), dim3(32, 8), 0, stream>>>(Vb, Vtb, 2048, 512);

  flash<<<dim3(32, 32), 256, 0, stream>>>(Qb, Kb, Vtb, Ctx);

  // O-projection: bf16 A (Ctx), fp32 output
  gemm_bt<false, true><<<dim3(16, 32), 256, 0, stream>>>(
      Ctx, Ctx, wob, (float*)d_out, (float*)d_out, 2048, 2048, 2048, 4096, 2048, 2048);
}

// Round 6
// 485.460 us; speedup vs baseline: 1.1685x; 1.1685x over previous
//
#include <hip/hip_runtime.h>

typedef __bf16 bf16;
typedef __bf16 bf16x8 __attribute__((ext_vector_type(8)));
typedef float  f32x4  __attribute__((ext_vector_type(4)));

#define MFMA16(a, b, c) __builtin_amdgcn_mfma_f32_16x16x32_bf16((a), (b), (c), 0, 0, 0)

// async global->LDS, 16 B per lane: lane l -> ldsbase + l*16 (wave-uniform base).
__device__ inline void gl_lds16(const bf16* g, bf16* l) {
  __builtin_amdgcn_global_load_lds(
      (const __attribute__((address_space(1))) void*)g,
      (__attribute__((address_space(3))) void*)l, 16, 0, 0);
}

__device__ inline bf16x8 cvt8(const float* __restrict__ f) {
  float4 a = *(const float4*)f;
  float4 b = *(const float4*)(f + 4);
  bf16x8 r;
  r[0] = (bf16)a.x; r[1] = (bf16)a.y; r[2] = (bf16)a.z; r[3] = (bf16)a.w;
  r[4] = (bf16)b.x; r[5] = (bf16)b.y; r[6] = (bf16)b.z; r[7] = (bf16)b.w;
  return r;
}

// ---------------------------------------------------------------------------
__global__ void cvt_f32_bf16(const float* __restrict__ src, bf16* __restrict__ dst,
                             int n8) {
  int i = blockIdx.x * 256 + threadIdx.x;
  if (i >= n8) return;
  *(bf16x8*)(dst + (size_t)i * 8) = cvt8(src + (size_t)i * 8);
}

// ---------------------------------------------------------------------------
// GEMM: C[M,N] = A[M,K] @ W[N,K]^T, bf16 MFMA, fp32 accum.
// 128x128 tile, BK=64, 4 waves (2x2), 4x4 16x16x32 MFMA per wave.
// LDS in MFMA-FRAGMENT ORDER: 16 frags x 1KB per operand. Frag (mi,s):
// lane l holds A[m0+mi*16+(l&15)][k0+s*32+(l>>4)*8 ..+7]. Staged via
// global_load_lds (per-lane global gather, lane-contiguous LDS) -> fragment
// reads are `frag_base + lane*16`: ZERO bank conflicts (fix for r5's 16-way).
// AF32: A staged in same fragment order via VGPR cvt8 (fp32 source).
// Split output: blocks with n0 >= Nsplit use A1/C1 (fused K+V projection).
// ---------------------------------------------------------------------------
template <bool AF32, bool OUTF32>
__global__ __launch_bounds__(256) void gemm_bt(const void* __restrict__ Ap0,
                                               const void* __restrict__ Ap1,
                                               const bf16* __restrict__ W,
                                               void* __restrict__ C0,
                                               void* __restrict__ C1,
                                               int Nsplit, int ld0, int ld1,
                                               int M, int N, int K) {
  __shared__ alignas(16) bf16 As[16 * 512];   // 16 KB, fragment-ordered
  __shared__ alignas(16) bf16 Bs[16 * 512];

  const int tid  = threadIdx.x;
  const int wave = tid >> 6, lane = tid & 63;
  const int wm = wave >> 1, wn = wave & 1;
  const int lr = lane & 15, quad = lane >> 4;
  const int m0 = blockIdx.y * 128, n0 = blockIdx.x * 128;

  const bool second = (n0 >= Nsplit);
  const void* Ap = second ? Ap1 : Ap0;

  f32x4 vzero = {0.f, 0.f, 0.f, 0.f};
  f32x4 acc[4][4];
#pragma unroll
  for (int mt = 0; mt < 4; ++mt)
#pragma unroll
    for (int nt = 0; nt < 4; ++nt) acc[mt][nt] = vzero;

  for (int k0 = 0; k0 < K; k0 += 64) {
    // ---- stage B frags (wave w: chunks 4w..4w+3) ----
#pragma unroll
    for (int j = 0; j < 4; ++j) {
      int c = wave * 4 + j;               // frag id: mi = c>>1, s = c&1
      gl_lds16(W + (size_t)(n0 + (c >> 1) * 16 + lr) * K + k0 + (c & 1) * 32 + quad * 8,
               Bs + c * 512);
    }
    // ---- stage A frags ----
    if (AF32) {
#pragma unroll
      for (int j = 0; j < 4; ++j) {
        int c = wave * 4 + j;
        *(bf16x8*)(As + c * 512 + lane * 8) =
            cvt8((const float*)Ap + (size_t)(m0 + (c >> 1) * 16 + lr) * K +
                 k0 + (c & 1) * 32 + quad * 8);
      }
    } else {
#pragma unroll
      for (int j = 0; j < 4; ++j) {
        int c = wave * 4 + j;
        gl_lds16((const bf16*)Ap + (size_t)(m0 + (c >> 1) * 16 + lr) * K +
                     k0 + (c & 1) * 32 + quad * 8,
                 As + c * 512);
      }
    }
    __syncthreads();

#pragma unroll
    for (int s = 0; s < 2; ++s) {
      bf16x8 af[4], bfg[4];
#pragma unroll
      for (int mt = 0; mt < 4; ++mt)
        af[mt] = *(const bf16x8*)(As + ((wm * 4 + mt) * 2 + s) * 512 + lane * 8);
#pragma unroll
      for (int nt = 0; nt < 4; ++nt)
        bfg[nt] = *(const bf16x8*)(Bs + ((wn * 4 + nt) * 2 + s) * 512 + lane * 8);
#pragma unroll
      for (int mt = 0; mt < 4; ++mt)
#pragma unroll
        for (int nt = 0; nt < 4; ++nt)
          acc[mt][nt] = MFMA16(af[mt], bfg[nt], acc[mt][nt]);
    }
    __syncthreads();
  }

  // epilogue: C/D layout col = lane&15, row = quad*4 + e   [HW-verified m89]
  void* Cb = second ? C1 : C0;
  const int ld = second ? ld1 : ld0;
  const int nb = second ? n0 - Nsplit : n0;
#pragma unroll
  for (int mt = 0; mt < 4; ++mt) {
    int row = m0 + wm * 64 + mt * 16 + quad * 4;
#pragma unroll
    for (int nt = 0; nt < 4; ++nt) {
      int col = nb + wn * 64 + nt * 16 + lr;
#pragma unroll
      for (int e = 0; e < 4; ++e) {
        if (OUTF32)
          ((float*)Cb)[(size_t)(row + e) * ld + col] = acc[mt][nt][e];
        else
          ((bf16*)Cb)[(size_t)(row + e) * ld + col] = (bf16)acc[mt][nt][e];
      }
    }
  }
}

// ---------------------------------------------------------------------------
// RoPE + clip (+scale fold), in place, vectorized: 8 (j,j+64) pairs/thread.
// ---------------------------------------------------------------------------
__global__ void rope_clip(bf16* __restrict__ X, int heads, float scl) {
  int tpr = heads * 8;
  int idx = blockIdx.x * 256 + threadIdx.x;
  if (idx >= 4096 * tpr) return;
  int r = idx / tpr;
  int rem = idx - r * tpr;
  int h = rem >> 3, j0 = (rem & 7) * 8;
  int l = r & 2047;
  size_t base = (size_t)r * (heads * 128) + h * 128 + j0;
  bf16x8 x1 = *(const bf16x8*)(X + base);
  bf16x8 x2 = *(const bf16x8*)(X + base + 64);
  bf16x8 y1, y2;
#pragma unroll
  for (int t = 0; t < 8; ++t) {
    int j = j0 + t;
    float inv = expf(-(float)j * (9.210340371976184f / 64.0f));
    float s, c;
    sincosf((float)l * inv, &s, &c);
    float a = (float)x1[t], b = (float)x2[t];
    float u = a * c - b * s;
    float v = a * s + b * c;
    y1[t] = (bf16)(fminf(fmaxf(u, -50.f), 50.f) * scl);
    y2[t] = (bf16)(fminf(fmaxf(v, -50.f), 50.f) * scl);
  }
  *(bf16x8*)(X + base)      = y1;
  *(bf16x8*)(X + base + 64) = y2;
}

// ---------------------------------------------------------------------------
// Transpose per batch: in (R x Cc) -> out (Cc x R).
// ---------------------------------------------------------------------------
__global__ void transpose_bf16(const bf16* __restrict__ in, bf16* __restrict__ out,
                               int R, int Cc) {
  __shared__ bf16 t[32][33];
  int b = blockIdx.z;
  const bf16* ip = in + (size_t)b * R * Cc;
  bf16* op = out + (size_t)b * R * Cc;
  int c0 = blockIdx.x * 32, r0 = blockIdx.y * 32;
  int lx = threadIdx.x, ly = threadIdx.y;
#pragma unroll
  for (int i = 0; i < 32; i += 8)
    t[ly + i][lx] = ip[(size_t)(r0 + ly + i) * Cc + c0 + lx];
  __syncthreads();
#pragma unroll
  for (int i = 0; i < 32; i += 8)
    op[(size_t)(c0 + ly + i) * R + r0 + lx] = t[lx][ly + i];
}

// ---------------------------------------------------------------------------
// Flash v4, causal, GQA (16 qh -> 4 kvh), DK=128, L=2048.
// 512 thr = 8 waves; 128 q-rows/block (16/wave); 64-key chunks (halves
// chunk count vs 64-row blocks). Fixed-max softmax (v2-verified).
// K/V staged FRAGMENT-ORDERED via global_load_lds: K frags (kt,ks) 16x1KB,
// V frags (dt,ks2) 16x1KB -> conflict-free lane*16 reads.
// P keeps the v2 stride-72 padded LDS round-trip.  Balanced causal swizzle.
// ---------------------------------------------------------------------------
__global__ __launch_bounds__(512) void flash(const bf16* __restrict__ Q,
                                             const bf16* __restrict__ Kp,
                                             const bf16* __restrict__ Vt,
                                             bf16* __restrict__ Ctx) {
  __shared__ alignas(16) bf16 Ks[16 * 512];   // 16 KB
  __shared__ alignas(16) bf16 Vs[16 * 512];   // 16 KB
  __shared__ alignas(16) bf16 Ps[8 * 16 * 72];

  const int tid  = threadIdx.x;
  const int wave = tid >> 6, lane = tid & 63;
  const int lr = lane & 15, quad = lane >> 4;
  const int bh = blockIdx.y;
  const int b = bh >> 4, h = bh & 15, hk = h >> 2;
  const int ix = blockIdx.x;
  const int qt = (ix & 1) ? (15 - (ix >> 1)) : (ix >> 1);  // balance causal work
  const int q0 = qt * 128;
  const int qb = q0 + wave * 16;

  const bf16* qptr = Q + ((size_t)(b * 2048 + qb + lr)) * 2048 + h * 128 + quad * 8;
  bf16x8 qf[4];
#pragma unroll
  for (int ks = 0; ks < 4; ++ks) qf[ks] = *(const bf16x8*)(qptr + ks * 32);

  f32x4 vzero = {0.f, 0.f, 0.f, 0.f};
  f32x4 o[8];
#pragma unroll
  for (int dt = 0; dt < 8; ++dt) o[dt] = vzero;
  float fls[4] = {0.f, 0.f, 0.f, 0.f};

  const bf16* kbase = Kp + (size_t)(b * 2048) * 512 + hk * 128;
  const bf16* vbase = Vt + ((size_t)(b * 512 + hk * 128)) * 2048;

  const int kmax = q0 + 128;
  for (int k0 = 0; k0 < kmax; k0 += 64) {
    // stage 32 frag-chunks (16 K + 16 V), 4 per wave, fragment-ordered
#pragma unroll
    for (int j = 0; j < 4; ++j) {
      int c = wave * 4 + j;
      if (c < 16) {  // K frag: kt = c>>2, ks = c&3
        gl_lds16(kbase + (size_t)(k0 + (c >> 2) * 16 + lr) * 512 + (c & 3) * 32 + quad * 8,
                 Ks + c * 512);
      } else {       // V frag: dt = (c-16)>>1, ks2 = (c-16)&1
        int c2 = c - 16;
        gl_lds16(vbase + (size_t)((c2 >> 1) * 16 + lr) * 2048 + k0 + (c2 & 1) * 32 + quad * 8,
                 Vs + c2 * 512);
      }
    }
    __syncthreads();

    if (k0 <= qb + 15) {  // wave-uniform causal skip
      f32x4 s[4] = {vzero, vzero, vzero, vzero};
#pragma unroll
      for (int ks = 0; ks < 4; ++ks) {
#pragma unroll
        for (int kt = 0; kt < 4; ++kt) {
          bf16x8 kf = *(const bf16x8*)(Ks + (kt * 4 + ks) * 512 + lane * 8);
          s[kt] = MFMA16(qf[ks], kf, s[kt]);
        }
      }
      bf16* pw = Ps + wave * (16 * 72);
#pragma unroll
      for (int kt = 0; kt < 4; ++kt) {
        int kid = k0 + kt * 16 + lr;
#pragma unroll
        for (int e = 0; e < 4; ++e) {
          int qi = qb + quad * 4 + e;
          float p = (kid <= qi) ? __expf(s[kt][e]) : 0.f;
          fls[e] += p;
          pw[(quad * 4 + e) * 72 + kt * 16 + lr] = (bf16)p;
        }
      }
#pragma unroll
      for (int ks2 = 0; ks2 < 2; ++ks2) {
        bf16x8 pf = *(const bf16x8*)(pw + lr * 72 + ks2 * 32 + quad * 8);
#pragma unroll
        for (int dt = 0; dt < 8; ++dt) {
          bf16x8 vf = *(const bf16x8*)(Vs + (dt * 2 + ks2) * 512 + lane * 8);
          o[dt] = MFMA16(pf, vf, o[dt]);
        }
      }
    }
    __syncthreads();
  }

  // one-time denominator reduce across the 16 key-lanes
#pragma unroll
  for (int e = 0; e < 4; ++e) {
    float s = fls[e];
    s += __shfl_xor(s, 1);
    s += __shfl_xor(s, 2);
    s += __shfl_xor(s, 4);
    s += __shfl_xor(s, 8);
    fls[e] = 1.0f / s;
  }

  bf16* cptr = Ctx + ((size_t)(b * 2048 + qb + quad * 4)) * 2048 + h * 128 + lr;
#pragma unroll
  for (int dt = 0; dt < 8; ++dt)
#pragma unroll
    for (int e = 0; e < 4; ++e)
      cptr[(size_t)e * 2048 + dt * 16] = (bf16)(o[dt][e] * fls[e]);
}

// ---------------------------------------------------------------------------
extern "C" void kernel_launch(void* const* d_in, const int* in_sizes, int n_in,
                              void* d_out, int out_size, void* d_ws, size_t ws_size,
                              hipStream_t stream) {
  (void)in_sizes; (void)n_in; (void)out_size; (void)ws_size;
  const float* query = (const float*)d_in[0];
  const float* key_t = (const float*)d_in[1];
  const float* value = (const float*)d_in[2];
  // d_in[3] = mask (causal tril) — applied analytically
  const float* Wq = (const float*)d_in[4];
  const float* Wk = (const float*)d_in[5];
  const float* Wv = (const float*)d_in[6];
  const float* Wo = (const float*)d_in[7];

  const size_t MB = 1024ull * 1024ull;
  char* ws  = (char*)d_ws;
  bf16* qbf = (bf16*)(ws);                  // [0,16)  query bf16
  bf16* wqb = (bf16*)(ws + 16 * MB);        // [16,24)
  bf16* wkb = (bf16*)(ws + 24 * MB);        // [24,26)  Wk bf16
  bf16* wvb = (bf16*)(ws + 26 * MB);        // [26,28)  Wv bf16 (contiguous with Wk)
  bf16* wob = (bf16*)(ws + 28 * MB);        // [28,36)
  bf16* Qb  = (bf16*)(ws + 36 * MB);        // [36,52)
  bf16* Kb  = (bf16*)(ws + 52 * MB);        // [52,56)
  bf16* Vb  = (bf16*)(ws + 56 * MB);        // [56,60)
  bf16* Vtb = (bf16*)(ws + 60 * MB);        // [60,64)
  bf16* Ctx = qbf;                          // alias: qbf dead after Q-proj

  cvt_f32_bf16<<<4096, 256, 0, stream>>>(query, qbf, 1048576);
  cvt_f32_bf16<<<2048, 256, 0, stream>>>(Wq, wqb, 524288);
  cvt_f32_bf16<<<512, 256, 0, stream>>>(Wk, wkb, 131072);
  cvt_f32_bf16<<<512, 256, 0, stream>>>(Wv, wvb, 131072);
  cvt_f32_bf16<<<2048, 256, 0, stream>>>(Wo, wob, 524288);

  // Q-projection: pure-bf16, both operands via fragment-ordered global_load_lds
  gemm_bt<false, false><<<dim3(16, 32), 256, 0, stream>>>(
      qbf, qbf, wqb, Qb, Qb, 2048, 2048, 2048, 4096, 2048, 2048);

  // fused K+V projection: N=1024 (Wk||Wv), A = key_t / value per half, fp32 A
  gemm_bt<true, false><<<dim3(8, 32), 256, 0, stream>>>(
      key_t, value, wkb, Kb, Vb, 512, 512, 512, 4096, 1024, 2048);

  rope_clip<<<2048, 256, 0, stream>>>(Qb, 16, 0.08838834764831845f);
  rope_clip<<<512, 256, 0, stream>>>(Kb, 4, 1.0f);

  transpose_bf16<<<dim3(16, 64, 2), dim3(32, 8), 0, stream>>>(Vb, Vtb, 2048, 512);

  flash<<<dim3(16, 32), 512, 0, stream>>>(Qb, Kb, Vtb, Ctx);

  // O-projection: bf16 A (Ctx), fp32 output
  gemm_bt<false, true><<<dim3(16, 32), 256, 0, stream>>>(
      Ctx, Ctx, wob, (float*)d_out, (float*)d_out, 2048, 2048, 2048, 4096, 2048, 2048);
}